// Round 5
// baseline (548.707 us; speedup 1.0000x reference)
//
#include <hip/hip_runtime.h>
#include <hip/hip_bf16.h>
#include <stdint.h>

// Problem constants
#define B_   4
#define S_   4096
#define D_   1280
#define H_   20
#define HD_  64
#define SKV_ 77
#define CD_  2048

typedef short bfrag8 __attribute__((ext_vector_type(8)));   // 8 bf16 = 4 VGPRs
typedef float f32x4  __attribute__((ext_vector_type(4)));

__device__ __forceinline__ float bf2f(unsigned short h) {
  return __uint_as_float(((unsigned int)h) << 16);
}
__device__ __forceinline__ unsigned short f2bf(float f) {
  unsigned int u = __float_as_uint(f);
  unsigned int r = (u + 0x7FFFu + ((u >> 16) & 1u)) >> 16;  // RNE
  return (unsigned short)r;
}
__device__ __forceinline__ float cvtlo(unsigned int u) { return __uint_as_float(u << 16); }
__device__ __forceinline__ float cvthi(unsigned int u) { return __uint_as_float(u & 0xFFFF0000u); }

// async global->LDS, 16B per lane. LDS dest = wave-uniform base + lane*16.
__device__ __forceinline__ void async16(const unsigned short* g, unsigned short* l) {
  __builtin_amdgcn_global_load_lds(
      (const __attribute__((address_space(1))) unsigned int*)g,
      (__attribute__((address_space(3))) unsigned int*)l, 16, 0, 0);
}

// ---------------------------------------------------------------------------
// prep_k: ALL pre-GEMM work in ONE launch (kills ~4 launch gaps).
//   blockIdx.y 0..5 : fp32->bf16 linear converts (grid-stride)
//   blockIdx.y 6..7 : fp32 [1280,1280] -> bf16 transposed [1280,1280]
//   blockIdx.y 8    : boost scalar (block x==0 only)
// ---------------------------------------------------------------------------
struct PrepArgs {
  const float* csrc[6]; unsigned short* cdst[6]; int cn4[6];
  const float* tsrc[2]; unsigned short* tdst[2];
  const float* mask; float* boostp;
};

__global__ __launch_bounds__(256) void prep_k(PrepArgs a) {
  const int y = blockIdx.y;
  if (y < 6) {
    const float* __restrict__ src = a.csrc[y];
    unsigned short* __restrict__ dst = a.cdst[y];
    const int n4 = a.cn4[y];
    for (int i = blockIdx.x * 256 + threadIdx.x; i < n4; i += gridDim.x * 256) {
      float4 v = ((const float4*)src)[i];
      uint2 o;
      o.x = (unsigned int)f2bf(v.x) | ((unsigned int)f2bf(v.y) << 16);
      o.y = (unsigned int)f2bf(v.z) | ((unsigned int)f2bf(v.w) << 16);
      ((uint2*)dst)[i] = o;
    }
  } else if (y < 8) {
    if (blockIdx.x >= 40 * 40) return;
    const float* __restrict__ src = a.tsrc[y - 6];
    unsigned short* __restrict__ dst = a.tdst[y - 6];
    __shared__ float t[32][33];
    const int k0 = (blockIdx.x / 40) * 32, n0 = (blockIdx.x % 40) * 32;
    const int r = threadIdx.x >> 3, c4 = threadIdx.x & 7;
    float4 v = *(const float4*)(src + (size_t)(k0 + r) * D_ + n0 + c4 * 4);
    t[r][c4 * 4 + 0] = v.x; t[r][c4 * 4 + 1] = v.y;
    t[r][c4 * 4 + 2] = v.z; t[r][c4 * 4 + 3] = v.w;
    __syncthreads();
    uint2 o;
    o.x = (unsigned int)f2bf(t[c4 * 4 + 0][r]) | ((unsigned int)f2bf(t[c4 * 4 + 1][r]) << 16);
    o.y = (unsigned int)f2bf(t[c4 * 4 + 2][r]) | ((unsigned int)f2bf(t[c4 * 4 + 3][r]) << 16);
    *(uint2*)(dst + (size_t)(n0 + r) * D_ + k0 + c4 * 4) = o;
  } else {
    if (blockIdx.x != 0) return;
    __shared__ float red[4];
    float s = 0.f;
    for (int i = threadIdx.x; i < S_; i += 256) s += a.mask[i];
#pragma unroll
    for (int off = 32; off > 0; off >>= 1) s += __shfl_down(s, off, 64);
    int wave = threadIdx.x >> 6, lane = threadIdx.x & 63;
    if (lane == 0) red[wave] = s;
    __syncthreads();
    if (threadIdx.x == 0) {
      float t = red[0] + red[1] + red[2] + red[3];
      float ratio = t * (1.0f / (float)S_);
      float boost = (ratio > 1e-6f && ratio < 0.1f)
                        ? fminf(1.0f + (0.1f - ratio) * 30.0f, 4.0f)
                        : 1.0f;
      a.boostp[0] = boost;
    }
  }
}

// ---------------------------------------------------------------------------
// Deep-pipelined counted-vmcnt GEMM: C[M,N] = A[M,K] @ Bt[N,K]^T (+bias).
// BM=256 BN=128, half-tile BK=32. 512 threads = 8 waves (4M x 2N), 64x64/wave.
// 4 LDS half-buffers (96 KB -> 1 block/CU), prefetch depth 3 half-tiles,
// boundary s_waitcnt vmcnt(6) (3 loads/thread/half-tile; never 0 in steady
// state), raw s_barrier, setprio(1) around MFMA clusters.
// T2 chunk swizzle (slot kc holds global chunk (kc-(row>>1))&3) BOTH sides:
// pre-swizzled global source (LDS dest linear for global_load_lds) + swizzled
// ds_read chunk ch=(quad+(l16>>1))&3 -> 0 bank conflicts (measured r3/r4).
// Identical phase/barrier structure to the round-3-verified kernel; only the
// ring depth (3->4) and prefetch distance (2->3) changed.
// Requires M%256==0, N%128==0, K%32==0, K/32 >= 3, grid%8==0.
// ---------------------------------------------------------------------------
__global__ __launch_bounds__(512, 2) void gemm4b(
    const unsigned short* __restrict__ A, const unsigned short* __restrict__ Bt,
    void* __restrict__ C, int M, int N, int K,
    const float* __restrict__ bias, int f32out) {
  __shared__ unsigned short Asm[4 * 256 * 32];  // 65536 B
  __shared__ unsigned short Bsm[4 * 128 * 32];  // 32768 B

  const int tid = threadIdx.x;
  const int nb = N >> 7;  // N/128
  int wg = blockIdx.x;
  {  // XCD-aware swizzle (grid % 8 == 0 at all call sites: 640)
    int cpx = gridDim.x >> 3;
    wg = (wg & 7) * cpx + (wg >> 3);
  }
  const int m0 = (wg / nb) * 256, n0 = (wg % nb) * 128;

  const int wave = tid >> 6, lane = tid & 63;
  const int wm = (wave >> 1) * 64, wn = (wave & 1) * 64;
  const int l16 = lane & 15, quad = lane >> 4;

  // staging: chunk c -> row = c>>2, LDS slot kc = c&3.
  const int r0 = tid >> 2;
  // swizzled global k-chunk for this thread's LDS slot (constant per thread;
  // second A chunk is row+128 -> same (row>>1)&3 mod 4)
  const int gch = ((tid & 3) - (tid >> 3)) & 3;
  // swizzled ds_read chunk (constant per lane; (row>>1)&3 == (l16>>1)&3)
  const int ch = (quad + (l16 >> 1)) & 3;

  const unsigned short* srcA = A + (size_t)(m0 + r0) * K + gch * 8;
  const unsigned short* srcB = Bt + (size_t)(n0 + r0) * K + gch * 8;

  const int NH = K >> 5;  // half-tiles

  // per-half-tile staging: A = 2 loads/thread, B = 1 load/thread (3 units)
  auto stageA = [&](unsigned short* dst, int h) {
    const unsigned short* s = srcA + h * 32;
    async16(s, dst + tid * 8);
    async16(s + (size_t)128 * K, dst + (512 + tid) * 8);
  };
  auto stageB = [&](unsigned short* dst, int h) {
    async16(srcB + h * 32, dst + tid * 8);
  };

  f32x4 acc[4][4] = {};

  // prologue: stage half-tiles 0,1,2 (9 loads outstanding)
  stageA(Asm + 0 * 8192, 0); stageB(Bsm + 0 * 4096, 0);
  stageA(Asm + 1 * 8192, 1); stageB(Bsm + 1 * 4096, 1);
  stageA(Asm + 2 * 8192, 2); stageB(Bsm + 2 * 4096, 2);
  asm volatile("s_waitcnt vmcnt(6)" ::: "memory");  // half-tile 0 landed
  __builtin_amdgcn_s_barrier();

  for (int h = 0; h < NH; ++h) {
    unsigned short* cura = Asm + (h & 3) * 8192;
    unsigned short* curb = Bsm + (h & 3) * 4096;
    const int hp = h + 3;
    const bool pre = hp < NH;
    unsigned short* pa = Asm + (hp & 3) * 8192;
    unsigned short* pb = Bsm + (hp & 3) * 4096;

    // ---- phase A: frags m0,m1 + all B frags; issue A-prefetch of h+3
    bfrag8 af0 = *(const bfrag8*)(cura + (wm + 0 * 16 + l16) * 32 + ch * 8);
    bfrag8 af1 = *(const bfrag8*)(cura + (wm + 1 * 16 + l16) * 32 + ch * 8);
    bfrag8 bf[4];
#pragma unroll
    for (int nt = 0; nt < 4; ++nt)
      bf[nt] = *(const bfrag8*)(curb + (wn + nt * 16 + l16) * 32 + ch * 8);
    if (pre) stageA(pa, hp);
    __builtin_amdgcn_s_barrier();
    __builtin_amdgcn_s_setprio(1);
#pragma unroll
    for (int nt = 0; nt < 4; ++nt) {
      acc[0][nt] = __builtin_amdgcn_mfma_f32_16x16x32_bf16(af0, bf[nt], acc[0][nt], 0, 0, 0);
      acc[1][nt] = __builtin_amdgcn_mfma_f32_16x16x32_bf16(af1, bf[nt], acc[1][nt], 0, 0, 0);
    }
    __builtin_amdgcn_s_setprio(0);
    __builtin_amdgcn_s_barrier();
    // ---- phase B: frags m2,m3; issue B-prefetch of h+3
    bfrag8 af2 = *(const bfrag8*)(cura + (wm + 2 * 16 + l16) * 32 + ch * 8);
    bfrag8 af3 = *(const bfrag8*)(cura + (wm + 3 * 16 + l16) * 32 + ch * 8);
    if (pre) stageB(pb, hp);
    __builtin_amdgcn_s_barrier();
    __builtin_amdgcn_s_setprio(1);
#pragma unroll
    for (int nt = 0; nt < 4; ++nt) {
      acc[2][nt] = __builtin_amdgcn_mfma_f32_16x16x32_bf16(af2, bf[nt], acc[2][nt], 0, 0, 0);
      acc[3][nt] = __builtin_amdgcn_mfma_f32_16x16x32_bf16(af3, bf[nt], acc[3][nt], 0, 0, 0);
    }
    __builtin_amdgcn_s_setprio(0);
    // ---- boundary: ensure half-tile h+1 landed (counted, not drain)
    if (h + 1 < NH) {
      int inflight = NH - 2 - h;  // issued half-tiles beyond h+1
      if (inflight >= 2)      { asm volatile("s_waitcnt vmcnt(6)" ::: "memory"); }
      else if (inflight == 1) { asm volatile("s_waitcnt vmcnt(3)" ::: "memory"); }
      else                    { asm volatile("s_waitcnt vmcnt(0)" ::: "memory"); }
      __builtin_amdgcn_s_barrier();
    }
  }

  // epilogue: D row = quad*4 + r, col = lane&15
#pragma unroll
  for (int mt = 0; mt < 4; ++mt) {
#pragma unroll
    for (int nt = 0; nt < 4; ++nt) {
#pragma unroll
      for (int r = 0; r < 4; ++r) {
        int row = m0 + wm + mt * 16 + quad * 4 + r;
        int col = n0 + wn + nt * 16 + l16;
        float v = acc[mt][nt][r];
        if (bias) v += bias[col];
        if (f32out) ((float*)C)[(size_t)row * N + col] = v;
        else ((unsigned short*)C)[(size_t)row * N + col] = f2bf(v);
      }
    }
  }
}

// ---------------------------------------------------------------------------
// small GEMM for the 4 KV projections (M=308), merged into one launch:
// blockIdx.z selects weight/output. 64x64 tile, bounds-checked M.
// ---------------------------------------------------------------------------
struct KVArgs { const unsigned short* W[4]; unsigned short* O[4]; };
__global__ __launch_bounds__(256) void gemm_kv4(
    const unsigned short* __restrict__ A, KVArgs kv, int M, int N, int K) {
  const unsigned short* __restrict__ Bw = kv.W[blockIdx.z];
  unsigned short* __restrict__ C = kv.O[blockIdx.z];
  __shared__ unsigned short As[64][40];
  __shared__ unsigned short Bs[64][40];

  const int tid = threadIdx.x;
  const int m0 = blockIdx.x * 64, n0 = blockIdx.y * 64;
  const int wave = tid >> 6, lane = tid & 63;
  const int l16 = lane & 15, quad = lane >> 4;

  f32x4 acc[4] = {};

  for (int k0 = 0; k0 < K; k0 += 32) {
    {
      int row = tid >> 2, kc = tid & 3;
      int gr = m0 + row;
      uint4 v = make_uint4(0u, 0u, 0u, 0u);
      if (gr < M) v = *(const uint4*)(A + (size_t)gr * K + k0 + kc * 8);
      *(uint4*)&As[row][kc * 8] = v;
    }
    {
      int kk = tid >> 3, n8 = tid & 7;
      uint4 v = *(const uint4*)(Bw + (size_t)(k0 + kk) * N + n0 + n8 * 8);
      unsigned short* p = (unsigned short*)&v;
#pragma unroll
      for (int j = 0; j < 8; ++j) Bs[n8 * 8 + j][kk] = p[j];
    }
    __syncthreads();

    bfrag8 af = *(const bfrag8*)&As[wave * 16 + l16][quad * 8];
#pragma unroll
    for (int nt = 0; nt < 4; ++nt) {
      bfrag8 bf = *(const bfrag8*)&Bs[nt * 16 + l16][quad * 8];
      acc[nt] = __builtin_amdgcn_mfma_f32_16x16x32_bf16(af, bf, acc[nt], 0, 0, 0);
    }
    __syncthreads();
  }

#pragma unroll
  for (int nt = 0; nt < 4; ++nt) {
#pragma unroll
    for (int r = 0; r < 4; ++r) {
      int row = m0 + wave * 16 + quad * 4 + r;
      if (row < M) {
        int col = n0 + nt * 16 + l16;
        C[(size_t)row * N + col] = f2bf(acc[nt][r]);
      }
    }
  }
}

// ---------------------------------------------------------------------------
// Attention v4: MFMA-based. One block = 64 q-rows of one (b,h); 4 waves, each
// wave owns 16 q-rows. SKV=77 padded to 80 (scores) / 96 (PV k-steps).
// ---------------------------------------------------------------------------
__global__ __launch_bounds__(256, 2) void attn_k(
    const unsigned short* __restrict__ Q, const unsigned short* __restrict__ Kb,
    const unsigned short* __restrict__ Vb, const unsigned short* __restrict__ Kip,
    const unsigned short* __restrict__ Vip, const float* __restrict__ mask,
    const float* __restrict__ boostp, unsigned short* __restrict__ hs) {
  __shared__ unsigned short Ks0[80 * 88];    // 14080 B, row k stride 88 (2-way max)
  __shared__ unsigned short Ks1[80 * 88];
  __shared__ unsigned short VT0[64 * 104];   // 13312 B, row d stride 104 (2-way max)
  __shared__ unsigned short VT1[64 * 104];
  __shared__ unsigned short Ps[4 * 16 * 104];  // per-wave P tile [16 q][104 k]

  const int tid = threadIdx.x;
  const int bh = blockIdx.y;
  const int b = bh / H_, h = bh % H_;
  const int qb = blockIdx.x * 64;
  const int wave = tid >> 6, lane = tid & 63;
  const int l16 = lane & 15, quad = lane >> 4;

  bfrag8 qf[2];
  {
    const unsigned short* qp =
        Q + (size_t)(b * S_ + qb + wave * 16 + l16) * D_ + h * HD_ + quad * 8;
    qf[0] = *(const bfrag8*)(qp);
    qf[1] = *(const bfrag8*)(qp + 32);
  }

  auto stageK = [&](const unsigned short* src, unsigned short* dst) {
    for (int idx = tid; idx < 640; idx += 256) {
      int row = idx >> 3, c = idx & 7;
      uint4 v = make_uint4(0u, 0u, 0u, 0u);
      if (row < SKV_)
        v = *(const uint4*)(src + (size_t)(b * SKV_ + row) * D_ + h * HD_ + c * 8);
      *(uint4*)(dst + row * 88 + c * 8) = v;
    }
  };
  auto stageVT = [&](const unsigned short* src, unsigned short* dst) {
    for (int idx = tid; idx < 384; idx += 256) {
      int kp = idx % 48, c = idx / 48;
      int k0 = kp * 2;
      uint4 a = make_uint4(0u, 0u, 0u, 0u), bb = make_uint4(0u, 0u, 0u, 0u);
      if (k0 < SKV_)
        a = *(const uint4*)(src + (size_t)(b * SKV_ + k0) * D_ + h * HD_ + c * 8);
      if (k0 + 1 < SKV_)
        bb = *(const uint4*)(src + (size_t)(b * SKV_ + k0 + 1) * D_ + h * HD_ + c * 8);
      const unsigned short* ap = (const unsigned short*)&a;
      const unsigned short* bp = (const unsigned short*)&bb;
#pragma unroll
      for (int j = 0; j < 8; ++j) {
        int d = c * 8 + j;
        *(unsigned int*)(dst + d * 104 + k0) =
            (unsigned int)ap[j] | ((unsigned int)bp[j] << 16);
      }
    }
  };

  stageK(Kb, Ks0);
  stageK(Kip, Ks1);
  stageVT(Vb, VT0);
  stageVT(Vip, VT1);

  {
    unsigned short* pw = Ps + wave * 16 * 104;
    int rr = lane >> 2, w4 = lane & 3;
    *(unsigned int*)(pw + rr * 104 + 80 + w4 * 4) = 0u;
    *(unsigned int*)(pw + rr * 104 + 82 + w4 * 4) = 0u;
  }
  __syncthreads();

  struct PVOut { f32x4 a[4]; float inv; };

  auto branch = [&](const unsigned short* KsL, const unsigned short* VTL) -> PVOut {
    f32x4 st[5] = {};
#pragma unroll
    for (int t = 0; t < 5; ++t) {
      const unsigned short* kb = KsL + (t * 16 + l16) * 88 + quad * 8;
      bfrag8 k0 = *(const bfrag8*)(kb);
      bfrag8 k1 = *(const bfrag8*)(kb + 32);
      st[t] = __builtin_amdgcn_mfma_f32_16x16x32_bf16(k0, qf[0], st[t], 0, 0, 0);
      st[t] = __builtin_amdgcn_mfma_f32_16x16x32_bf16(k1, qf[1], st[t], 0, 0, 0);
    }
    float p[5][4];
    float m = -1e30f;
#pragma unroll
    for (int t = 0; t < 5; ++t)
#pragma unroll
      for (int r = 0; r < 4; ++r) {
        float s = st[t][r] * 0.125f;
        if (t == 4 && r >= 1) s = (quad == 3) ? -1e30f : s;
        p[t][r] = s;
        m = fmaxf(m, s);
      }
    m = fmaxf(m, __shfl_xor(m, 16, 64));
    m = fmaxf(m, __shfl_xor(m, 32, 64));
    float l = 0.f;
#pragma unroll
    for (int t = 0; t < 5; ++t)
#pragma unroll
      for (int r = 0; r < 4; ++r) {
        float e = __expf(p[t][r] - m);
        p[t][r] = e;
        l += e;
      }
    l += __shfl_xor(l, 16, 64);
    l += __shfl_xor(l, 32, 64);

    unsigned short* prow = Ps + wave * 16 * 104 + l16 * 104 + quad * 4;
#pragma unroll
    for (int t = 0; t < 5; ++t) {
      __hip_bfloat162 h0 = __float22bfloat162_rn(make_float2(p[t][0], p[t][1]));
      __hip_bfloat162 h1 = __float22bfloat162_rn(make_float2(p[t][2], p[t][3]));
      unsigned int u0, u1;
      __builtin_memcpy(&u0, &h0, 4);
      __builtin_memcpy(&u1, &h1, 4);
      *(unsigned int*)(prow + t * 16) = u0;
      *(unsigned int*)(prow + t * 16 + 2) = u1;
    }
    __syncthreads();

    PVOut o;
    f32x4 acc[4] = {};
    const unsigned short* pbase = Ps + wave * 16 * 104 + l16 * 104;
#pragma unroll
    for (int ks = 0; ks < 3; ++ks) {
      bfrag8 pf = *(const bfrag8*)(pbase + ks * 32 + quad * 8);
#pragma unroll
      for (int dt = 0; dt < 4; ++dt) {
        bfrag8 vf = *(const bfrag8*)(VTL + (dt * 16 + l16) * 104 + ks * 32 + quad * 8);
        acc[dt] = __builtin_amdgcn_mfma_f32_16x16x32_bf16(pf, vf, acc[dt], 0, 0, 0);
      }
    }
#pragma unroll
    for (int dt = 0; dt < 4; ++dt) o.a[dt] = acc[dt];
    o.inv = 1.0f / l;
    return o;
  };

  PVOut o0 = branch(Ks0, VT0);
  __syncthreads();
  PVOut o1 = branch(Ks1, VT1);

  const float boost = boostp[0];
#pragma unroll
  for (int r = 0; r < 4; ++r) {
    const int s = qb + wave * 16 + quad * 4 + r;
    const float sc = mask[s] * boost;
    const float i0 = __shfl(o0.inv, quad * 4 + r, 64);
    const float i1 = __shfl(o1.inv, quad * 4 + r, 64);
    unsigned short* op = hs + (size_t)(b * S_ + s) * D_ + h * HD_ + l16;
#pragma unroll
    for (int dt = 0; dt < 4; ++dt) {
      float v = o0.a[dt][r] * i0 + sc * (o1.a[dt][r] * i1);
      op[dt * 16] = f2bf(v);
    }
  }
}

// ---------------------------------------------------------------------------
extern "C" void kernel_launch(void* const* d_in, const int* in_sizes, int n_in,
                              void* d_out, int out_size, void* d_ws, size_t ws_size,
                              hipStream_t stream) {
  const float* hidden = (const float*)d_in[0];
  const float* enc    = (const float*)d_in[1];
  const float* mask   = (const float*)d_in[2];
  const float* Wq     = (const float*)d_in[3];
  const float* Wk     = (const float*)d_in[4];
  const float* Wv     = (const float*)d_in[5];
  const float* Wkip   = (const float*)d_in[6];
  const float* Wvip   = (const float*)d_in[7];
  const float* Wo     = (const float*)d_in[8];
  const float* bo     = (const float*)d_in[9];

  char* ws = (char*)d_ws;
  unsigned short* cHid  = (unsigned short*)(ws + 0ULL);           // 41,943,040
  unsigned short* hsb   = cHid;                                   // alias (cHid dead after Q-proj)
  unsigned short* cEnc  = (unsigned short*)(ws + 41943040ULL);
  unsigned short* cWqT  = (unsigned short*)(ws + 43204608ULL);    // [N,K] transposed
  unsigned short* cWk   = (unsigned short*)(ws + 46481408ULL);
  unsigned short* cWv   = (unsigned short*)(ws + 51724288ULL);
  unsigned short* cWkip = (unsigned short*)(ws + 56967168ULL);
  unsigned short* cWvip = (unsigned short*)(ws + 62210048ULL);
  unsigned short* cWoT  = (unsigned short*)(ws + 67452928ULL);    // [N,K] transposed
  unsigned short* Qb    = (unsigned short*)(ws + 70729728ULL);
  unsigned short* Kb    = (unsigned short*)(ws + 112672768ULL);
  unsigned short* Vb    = (unsigned short*)(ws + 113461248ULL);
  unsigned short* Kip   = (unsigned short*)(ws + 114249728ULL);
  unsigned short* Vip   = (unsigned short*)(ws + 115038208ULL);
  float* boostp         = (float*)(ws + 115826688ULL);

  // ---- one prep launch: 6 converts + 2 transposes + boost
  {
    PrepArgs a;
    a.csrc[0] = hidden; a.cdst[0] = cHid;  a.cn4[0] = (B_ * S_ * D_) >> 2;
    a.csrc[1] = enc;    a.cdst[1] = cEnc;  a.cn4[1] = (B_ * SKV_ * CD_) >> 2;
    a.csrc[2] = Wk;     a.cdst[2] = cWk;   a.cn4[2] = (CD_ * D_) >> 2;
    a.csrc[3] = Wv;     a.cdst[3] = cWv;   a.cn4[3] = (CD_ * D_) >> 2;
    a.csrc[4] = Wkip;   a.cdst[4] = cWkip; a.cn4[4] = (CD_ * D_) >> 2;
    a.csrc[5] = Wvip;   a.cdst[5] = cWvip; a.cn4[5] = (CD_ * D_) >> 2;
    a.tsrc[0] = Wq; a.tdst[0] = cWqT;
    a.tsrc[1] = Wo; a.tdst[1] = cWoT;
    a.mask = mask; a.boostp = boostp;
    prep_k<<<dim3(2048, 9), dim3(256), 0, stream>>>(a);
  }

  const int MQ = B_ * S_;    // 16384
  const int MKV = B_ * SKV_; // 308

  // Q = hidden @ Wq  (grid 64*10 = 640, %8==0)
  gemm4b<<<dim3((MQ / 256) * (D_ / 128)), dim3(512), 0, stream>>>(
      cHid, cWqT, Qb, MQ, D_, D_, nullptr, 0);

  // 4 KV projections in one launch
  {
    KVArgs kv;
    kv.W[0] = cWk;   kv.O[0] = Kb;
    kv.W[1] = cWv;   kv.O[1] = Vb;
    kv.W[2] = cWkip; kv.O[2] = Kip;
    kv.W[3] = cWvip; kv.O[3] = Vip;
    gemm_kv4<<<dim3(5, 20, 4), dim3(256), 0, stream>>>(cEnc, kv, MKV, D_, CD_);
  }

  attn_k<<<dim3(S_ / 64, B_ * H_), dim3(256), 0, stream>>>(Qb, Kb, Vb, Kip, Vip,
                                                           mask, boostp, hsb);

  // out = hsb @ Wo + bo  (fp32 output)
  gemm4b<<<dim3((MQ / 256) * (D_ / 128)), dim3(512), 0, stream>>>(
      hsb, cWoT, d_out, MQ, D_, D_, bo, 1);
}

// Round 6
// 502.830 us; speedup vs baseline: 1.0912x; 1.0912x over previous
//
#include <hip/hip_runtime.h>
#include <hip/hip_bf16.h>
#include <stdint.h>

// Problem constants
#define B_   4
#define S_   4096
#define D_   1280
#define H_   20
#define HD_  64
#define SKV_ 77
#define CD_  2048

typedef short bfrag8 __attribute__((ext_vector_type(8)));   // 8 bf16 = 4 VGPRs
typedef float f32x4  __attribute__((ext_vector_type(4)));

__device__ __forceinline__ float bf2f(unsigned short h) {
  return __uint_as_float(((unsigned int)h) << 16);
}
__device__ __forceinline__ unsigned short f2bf(float f) {
  unsigned int u = __float_as_uint(f);
  unsigned int r = (u + 0x7FFFu + ((u >> 16) & 1u)) >> 16;  // RNE
  return (unsigned short)r;
}
__device__ __forceinline__ float cvtlo(unsigned int u) { return __uint_as_float(u << 16); }
__device__ __forceinline__ float cvthi(unsigned int u) { return __uint_as_float(u & 0xFFFF0000u); }

// async global->LDS, 16B per lane. LDS dest = wave-uniform base + lane*16.
__device__ __forceinline__ void async16(const unsigned short* g, unsigned short* l) {
  __builtin_amdgcn_global_load_lds(
      (const __attribute__((address_space(1))) unsigned int*)g,
      (__attribute__((address_space(3))) unsigned int*)l, 16, 0, 0);
}

// ---------------------------------------------------------------------------
// prep_k: ALL pre-GEMM work in ONE launch.
//   blockIdx.y 0..5 : fp32->bf16 linear converts (grid-stride)
//   blockIdx.y 6..7 : fp32 [1280,1280] -> bf16 transposed [1280,1280]
//   blockIdx.y 8    : boost scalar (block x==0 only)
// ---------------------------------------------------------------------------
struct PrepArgs {
  const float* csrc[6]; unsigned short* cdst[6]; int cn4[6];
  const float* tsrc[2]; unsigned short* tdst[2];
  const float* mask; float* boostp;
};

__global__ __launch_bounds__(256) void prep_k(PrepArgs a) {
  const int y = blockIdx.y;
  if (y < 6) {
    const float* __restrict__ src = a.csrc[y];
    unsigned short* __restrict__ dst = a.cdst[y];
    const int n4 = a.cn4[y];
    for (int i = blockIdx.x * 256 + threadIdx.x; i < n4; i += gridDim.x * 256) {
      float4 v = ((const float4*)src)[i];
      uint2 o;
      o.x = (unsigned int)f2bf(v.x) | ((unsigned int)f2bf(v.y) << 16);
      o.y = (unsigned int)f2bf(v.z) | ((unsigned int)f2bf(v.w) << 16);
      ((uint2*)dst)[i] = o;
    }
  } else if (y < 8) {
    if (blockIdx.x >= 40 * 40) return;
    const float* __restrict__ src = a.tsrc[y - 6];
    unsigned short* __restrict__ dst = a.tdst[y - 6];
    __shared__ float t[32][33];
    const int k0 = (blockIdx.x / 40) * 32, n0 = (blockIdx.x % 40) * 32;
    const int r = threadIdx.x >> 3, c4 = threadIdx.x & 7;
    float4 v = *(const float4*)(src + (size_t)(k0 + r) * D_ + n0 + c4 * 4);
    t[r][c4 * 4 + 0] = v.x; t[r][c4 * 4 + 1] = v.y;
    t[r][c4 * 4 + 2] = v.z; t[r][c4 * 4 + 3] = v.w;
    __syncthreads();
    uint2 o;
    o.x = (unsigned int)f2bf(t[c4 * 4 + 0][r]) | ((unsigned int)f2bf(t[c4 * 4 + 1][r]) << 16);
    o.y = (unsigned int)f2bf(t[c4 * 4 + 2][r]) | ((unsigned int)f2bf(t[c4 * 4 + 3][r]) << 16);
    *(uint2*)(dst + (size_t)(n0 + r) * D_ + k0 + c4 * 4) = o;
  } else {
    if (blockIdx.x != 0) return;
    __shared__ float red[4];
    float s = 0.f;
    for (int i = threadIdx.x; i < S_; i += 256) s += a.mask[i];
#pragma unroll
    for (int off = 32; off > 0; off >>= 1) s += __shfl_down(s, off, 64);
    int wave = threadIdx.x >> 6, lane = threadIdx.x & 63;
    if (lane == 0) red[wave] = s;
    __syncthreads();
    if (threadIdx.x == 0) {
      float t = red[0] + red[1] + red[2] + red[3];
      float ratio = t * (1.0f / (float)S_);
      float boost = (ratio > 1e-6f && ratio < 0.1f)
                        ? fminf(1.0f + (0.1f - ratio) * 30.0f, 4.0f)
                        : 1.0f;
      a.boostp[0] = boost;
    }
  }
}

// ---------------------------------------------------------------------------
// Round-3-verified phased counted-vmcnt GEMM (88 us): BM=256 BN=128 BK=32.
// 512 threads = 8 waves (4M x 2N), per-wave 64x64. 3 LDS buffers (72 KB ->
// 2 blocks/CU), prefetch distance 2, boundary s_waitcnt vmcnt(3), raw
// s_barrier, setprio around MFMA. T2 chunk swizzle both sides -> 0 conflicts.
// Requires M%256==0, N%128==0, K%32==0, K/32 >= 3, grid%8==0.
// ---------------------------------------------------------------------------
__global__ __launch_bounds__(512, 3) void gemm8p(
    const unsigned short* __restrict__ A, const unsigned short* __restrict__ Bt,
    void* __restrict__ C, int M, int N, int K,
    const float* __restrict__ bias, int f32out) {
  __shared__ unsigned short Asm[3 * 256 * 32];  // 49152 B
  __shared__ unsigned short Bsm[3 * 128 * 32];  // 24576 B

  const int tid = threadIdx.x;
  const int nb = N >> 7;  // N/128
  int wg = blockIdx.x;
  {  // XCD-aware swizzle (grid % 8 == 0)
    int cpx = gridDim.x >> 3;
    wg = (wg & 7) * cpx + (wg >> 3);
  }
  const int m0 = (wg / nb) * 256, n0 = (wg % nb) * 128;

  const int wave = tid >> 6, lane = tid & 63;
  const int wm = (wave >> 1) * 64, wn = (wave & 1) * 64;
  const int l16 = lane & 15, quad = lane >> 4;

  const int r0 = tid >> 2;
  const int gch = ((tid & 3) - (tid >> 3)) & 3;
  const int ch = (quad + (l16 >> 1)) & 3;

  const unsigned short* srcA = A + (size_t)(m0 + r0) * K + gch * 8;
  const unsigned short* srcB = Bt + (size_t)(n0 + r0) * K + gch * 8;

  unsigned short* pa0 = Asm;
  unsigned short* pa1 = Asm + 256 * 32;
  unsigned short* pa2 = Asm + 2 * 256 * 32;
  unsigned short* pb0 = Bsm;
  unsigned short* pb1 = Bsm + 128 * 32;
  unsigned short* pb2 = Bsm + 2 * 128 * 32;

  const int NT = K >> 5;

  auto stageA = [&](unsigned short* dst, int t) {
    const unsigned short* s = srcA + t * 32;
    async16(s, dst + tid * 8);
    async16(s + (size_t)128 * K, dst + (512 + tid) * 8);
  };
  auto stageB = [&](unsigned short* dst, int t) {
    async16(srcB + t * 32, dst + tid * 8);
  };

  f32x4 acc[4][4] = {};

  stageA(pa0, 0); stageB(pb0, 0);
  stageA(pa1, 1); stageB(pb1, 1);
  asm volatile("s_waitcnt vmcnt(3)" ::: "memory");  // tile 0 landed
  __builtin_amdgcn_s_barrier();

  for (int t = 0; t < NT; ++t) {
    const bool pre = (t + 2) < NT;
    bfrag8 af0 = *(const bfrag8*)(pa0 + (wm + 0 * 16 + l16) * 32 + ch * 8);
    bfrag8 af1 = *(const bfrag8*)(pa0 + (wm + 1 * 16 + l16) * 32 + ch * 8);
    bfrag8 bf[4];
#pragma unroll
    for (int nt = 0; nt < 4; ++nt)
      bf[nt] = *(const bfrag8*)(pb0 + (wn + nt * 16 + l16) * 32 + ch * 8);
    if (pre) stageA(pa2, t + 2);
    __builtin_amdgcn_s_barrier();
    __builtin_amdgcn_s_setprio(1);
#pragma unroll
    for (int nt = 0; nt < 4; ++nt) {
      acc[0][nt] = __builtin_amdgcn_mfma_f32_16x16x32_bf16(af0, bf[nt], acc[0][nt], 0, 0, 0);
      acc[1][nt] = __builtin_amdgcn_mfma_f32_16x16x32_bf16(af1, bf[nt], acc[1][nt], 0, 0, 0);
    }
    __builtin_amdgcn_s_setprio(0);
    __builtin_amdgcn_s_barrier();
    bfrag8 af2 = *(const bfrag8*)(pa0 + (wm + 2 * 16 + l16) * 32 + ch * 8);
    bfrag8 af3 = *(const bfrag8*)(pa0 + (wm + 3 * 16 + l16) * 32 + ch * 8);
    if (pre) stageB(pb2, t + 2);
    __builtin_amdgcn_s_barrier();
    __builtin_amdgcn_s_setprio(1);
#pragma unroll
    for (int nt = 0; nt < 4; ++nt) {
      acc[2][nt] = __builtin_amdgcn_mfma_f32_16x16x32_bf16(af2, bf[nt], acc[2][nt], 0, 0, 0);
      acc[3][nt] = __builtin_amdgcn_mfma_f32_16x16x32_bf16(af3, bf[nt], acc[3][nt], 0, 0, 0);
    }
    __builtin_amdgcn_s_setprio(0);
    if (t + 1 < NT) {
      if (pre) { asm volatile("s_waitcnt vmcnt(3)" ::: "memory"); }
      else     { asm volatile("s_waitcnt vmcnt(0)" ::: "memory"); }
      __builtin_amdgcn_s_barrier();
      unsigned short* ta = pa0; pa0 = pa1; pa1 = pa2; pa2 = ta;
      unsigned short* tb = pb0; pb0 = pb1; pb1 = pb2; pb2 = tb;
    }
  }

#pragma unroll
  for (int mt = 0; mt < 4; ++mt) {
#pragma unroll
    for (int nt = 0; nt < 4; ++nt) {
#pragma unroll
      for (int r = 0; r < 4; ++r) {
        int row = m0 + wm + mt * 16 + quad * 4 + r;
        int col = n0 + wn + nt * 16 + l16;
        float v = acc[mt][nt][r];
        if (bias) v += bias[col];
        if (f32out) ((float*)C)[(size_t)row * N + col] = v;
        else ((unsigned short*)C)[(size_t)row * N + col] = f2bf(v);
      }
    }
  }
}

// ---------------------------------------------------------------------------
// gemm_wide: SAME verified skeleton (ring-3, 2-phase, counted vmcnt, raw
// barriers, T2 swizzle both sides), but 256 threads = 4 waves (2M x 2N),
// per-wave 64x128 tile -> block 128x256. LDS reads per block-half-tile drop
// from 64 KB (gemm8p) to 48 KB for the same 2.1 MFLOP (A frags re-read 2x,
// B frags 2x instead of 4x). LDS 3*(128+256)*32*2 = 72 KB -> 2 blocks/CU.
// 6 DMA loads/thread/half-tile -> boundary vmcnt(6). acc[4][8] ~190 VGPR,
// statically indexed, fits 2 waves/SIMD.
// Requires M%128==0, N%256==0, K%32==0, K/32 >= 3, grid%8==0.
// ---------------------------------------------------------------------------
__global__ __launch_bounds__(256, 2) void gemm_wide(
    const unsigned short* __restrict__ A, const unsigned short* __restrict__ Bt,
    void* __restrict__ C, int M, int N, int K,
    const float* __restrict__ bias, int f32out) {
  __shared__ unsigned short Asm[3 * 128 * 32];  // 24576 B
  __shared__ unsigned short Bsm[3 * 256 * 32];  // 49152 B

  const int tid = threadIdx.x;
  const int nb = N >> 8;  // N/256
  int wg = blockIdx.x;
  {  // XCD-aware swizzle (grid % 8 == 0: 640)
    int cpx = gridDim.x >> 3;
    wg = (wg & 7) * cpx + (wg >> 3);
  }
  const int m0 = (wg / nb) * 128, n0 = (wg % nb) * 256;

  const int wave = tid >> 6, lane = tid & 63;
  const int wm = (wave >> 1) * 64, wn = (wave & 1) * 128;
  const int l16 = lane & 15, quad = lane >> 4;

  // staging: chunk c -> row = c>>2, LDS slot kc = c&3; extra chunks at
  // row+64k keep (row>>1)&3 mod 4 -> same gch applies.
  const int r0 = tid >> 2;
  const int gch = ((tid & 3) - (tid >> 3)) & 3;
  const int ch = (quad + (l16 >> 1)) & 3;

  const unsigned short* srcA = A + (size_t)(m0 + r0) * K + gch * 8;
  const unsigned short* srcB = Bt + (size_t)(n0 + r0) * K + gch * 8;

  unsigned short* pa0 = Asm;
  unsigned short* pa1 = Asm + 128 * 32;
  unsigned short* pa2 = Asm + 2 * 128 * 32;
  unsigned short* pb0 = Bsm;
  unsigned short* pb1 = Bsm + 256 * 32;
  unsigned short* pb2 = Bsm + 2 * 256 * 32;

  const int NT = K >> 5;

  // per-half-tile: A = 2 loads/thread, B = 4 loads/thread (6 vmcnt units)
  auto stageA = [&](unsigned short* dst, int t) {
    const unsigned short* s = srcA + t * 32;
    async16(s, dst + tid * 8);
    async16(s + (size_t)64 * K, dst + (256 + tid) * 8);
  };
  auto stageB = [&](unsigned short* dst, int t) {
    const unsigned short* s = srcB + t * 32;
    async16(s, dst + tid * 8);
    async16(s + (size_t)64 * K, dst + (256 + tid) * 8);
    async16(s + (size_t)128 * K, dst + (512 + tid) * 8);
    async16(s + (size_t)192 * K, dst + (768 + tid) * 8);
  };

  f32x4 acc[4][8] = {};

  stageA(pa0, 0); stageB(pb0, 0);
  stageA(pa1, 1); stageB(pb1, 1);
  asm volatile("s_waitcnt vmcnt(6)" ::: "memory");  // tile 0 landed
  __builtin_amdgcn_s_barrier();

  for (int t = 0; t < NT; ++t) {
    const bool pre = (t + 2) < NT;
    // ---- phase A: A frags m0,m1 + all 8 B frags; issue A-prefetch of t+2
    bfrag8 af0 = *(const bfrag8*)(pa0 + (wm + 0 * 16 + l16) * 32 + ch * 8);
    bfrag8 af1 = *(const bfrag8*)(pa0 + (wm + 1 * 16 + l16) * 32 + ch * 8);
    bfrag8 bf[8];
#pragma unroll
    for (int nt = 0; nt < 8; ++nt)
      bf[nt] = *(const bfrag8*)(pb0 + (wn + nt * 16 + l16) * 32 + ch * 8);
    if (pre) stageA(pa2, t + 2);
    __builtin_amdgcn_s_barrier();
    __builtin_amdgcn_s_setprio(1);
#pragma unroll
    for (int nt = 0; nt < 8; ++nt) {
      acc[0][nt] = __builtin_amdgcn_mfma_f32_16x16x32_bf16(af0, bf[nt], acc[0][nt], 0, 0, 0);
      acc[1][nt] = __builtin_amdgcn_mfma_f32_16x16x32_bf16(af1, bf[nt], acc[1][nt], 0, 0, 0);
    }
    __builtin_amdgcn_s_setprio(0);
    __builtin_amdgcn_s_barrier();
    // ---- phase B: A frags m2,m3; issue B-prefetch of t+2
    bfrag8 af2 = *(const bfrag8*)(pa0 + (wm + 2 * 16 + l16) * 32 + ch * 8);
    bfrag8 af3 = *(const bfrag8*)(pa0 + (wm + 3 * 16 + l16) * 32 + ch * 8);
    if (pre) stageB(pb2, t + 2);
    __builtin_amdgcn_s_barrier();
    __builtin_amdgcn_s_setprio(1);
#pragma unroll
    for (int nt = 0; nt < 8; ++nt) {
      acc[2][nt] = __builtin_amdgcn_mfma_f32_16x16x32_bf16(af2, bf[nt], acc[2][nt], 0, 0, 0);
      acc[3][nt] = __builtin_amdgcn_mfma_f32_16x16x32_bf16(af3, bf[nt], acc[3][nt], 0, 0, 0);
    }
    __builtin_amdgcn_s_setprio(0);
    // ---- boundary: ensure tile t+1 DMA landed (counted, not drain)
    if (t + 1 < NT) {
      if (pre) { asm volatile("s_waitcnt vmcnt(6)" ::: "memory"); }
      else     { asm volatile("s_waitcnt vmcnt(0)" ::: "memory"); }
      __builtin_amdgcn_s_barrier();
      unsigned short* ta = pa0; pa0 = pa1; pa1 = pa2; pa2 = ta;
      unsigned short* tb = pb0; pb0 = pb1; pb1 = pb2; pb2 = tb;
    }
  }

  // epilogue: D row = quad*4 + r, col = lane&15
#pragma unroll
  for (int mt = 0; mt < 4; ++mt) {
#pragma unroll
    for (int nt = 0; nt < 8; ++nt) {
#pragma unroll
      for (int r = 0; r < 4; ++r) {
        int row = m0 + wm + mt * 16 + quad * 4 + r;
        int col = n0 + wn + nt * 16 + l16;
        float v = acc[mt][nt][r];
        if (bias) v += bias[col];
        if (f32out) ((float*)C)[(size_t)row * N + col] = v;
        else ((unsigned short*)C)[(size_t)row * N + col] = f2bf(v);
      }
    }
  }
}

// ---------------------------------------------------------------------------
// small GEMM for the 4 KV projections (M=308), merged into one launch:
// blockIdx.z selects weight/output. 64x64 tile, bounds-checked M.
// ---------------------------------------------------------------------------
struct KVArgs { const unsigned short* W[4]; unsigned short* O[4]; };
__global__ __launch_bounds__(256) void gemm_kv4(
    const unsigned short* __restrict__ A, KVArgs kv, int M, int N, int K) {
  const unsigned short* __restrict__ Bw = kv.W[blockIdx.z];
  unsigned short* __restrict__ C = kv.O[blockIdx.z];
  __shared__ unsigned short As[64][40];
  __shared__ unsigned short Bs[64][40];

  const int tid = threadIdx.x;
  const int m0 = blockIdx.x * 64, n0 = blockIdx.y * 64;
  const int wave = tid >> 6, lane = tid & 63;
  const int l16 = lane & 15, quad = lane >> 4;

  f32x4 acc[4] = {};

  for (int k0 = 0; k0 < K; k0 += 32) {
    {
      int row = tid >> 2, kc = tid & 3;
      int gr = m0 + row;
      uint4 v = make_uint4(0u, 0u, 0u, 0u);
      if (gr < M) v = *(const uint4*)(A + (size_t)gr * K + k0 + kc * 8);
      *(uint4*)&As[row][kc * 8] = v;
    }
    {
      int kk = tid >> 3, n8 = tid & 7;
      uint4 v = *(const uint4*)(Bw + (size_t)(k0 + kk) * N + n0 + n8 * 8);
      unsigned short* p = (unsigned short*)&v;
#pragma unroll
      for (int j = 0; j < 8; ++j) Bs[n8 * 8 + j][kk] = p[j];
    }
    __syncthreads();

    bfrag8 af = *(const bfrag8*)&As[wave * 16 + l16][quad * 8];
#pragma unroll
    for (int nt = 0; nt < 4; ++nt) {
      bfrag8 bf = *(const bfrag8*)&Bs[nt * 16 + l16][quad * 8];
      acc[nt] = __builtin_amdgcn_mfma_f32_16x16x32_bf16(af, bf, acc[nt], 0, 0, 0);
    }
    __syncthreads();
  }

#pragma unroll
  for (int nt = 0; nt < 4; ++nt) {
#pragma unroll
    for (int r = 0; r < 4; ++r) {
      int row = m0 + wave * 16 + quad * 4 + r;
      if (row < M) {
        int col = n0 + nt * 16 + l16;
        C[(size_t)row * N + col] = f2bf(acc[nt][r]);
      }
    }
  }
}

// ---------------------------------------------------------------------------
// Attention v4: MFMA-based. One block = 64 q-rows of one (b,h); 4 waves, each
// wave owns 16 q-rows. SKV=77 padded to 80 (scores) / 96 (PV k-steps).
// ---------------------------------------------------------------------------
__global__ __launch_bounds__(256, 2) void attn_k(
    const unsigned short* __restrict__ Q, const unsigned short* __restrict__ Kb,
    const unsigned short* __restrict__ Vb, const unsigned short* __restrict__ Kip,
    const unsigned short* __restrict__ Vip, const float* __restrict__ mask,
    const float* __restrict__ boostp, unsigned short* __restrict__ hs) {
  __shared__ unsigned short Ks0[80 * 88];    // 14080 B, row k stride 88 (2-way max)
  __shared__ unsigned short Ks1[80 * 88];
  __shared__ unsigned short VT0[64 * 104];   // 13312 B, row d stride 104 (2-way max)
  __shared__ unsigned short VT1[64 * 104];
  __shared__ unsigned short Ps[4 * 16 * 104];  // per-wave P tile [16 q][104 k]

  const int tid = threadIdx.x;
  const int bh = blockIdx.y;
  const int b = bh / H_, h = bh % H_;
  const int qb = blockIdx.x * 64;
  const int wave = tid >> 6, lane = tid & 63;
  const int l16 = lane & 15, quad = lane >> 4;

  bfrag8 qf[2];
  {
    const unsigned short* qp =
        Q + (size_t)(b * S_ + qb + wave * 16 + l16) * D_ + h * HD_ + quad * 8;
    qf[0] = *(const bfrag8*)(qp);
    qf[1] = *(const bfrag8*)(qp + 32);
  }

  auto stageK = [&](const unsigned short* src, unsigned short* dst) {
    for (int idx = tid; idx < 640; idx += 256) {
      int row = idx >> 3, c = idx & 7;
      uint4 v = make_uint4(0u, 0u, 0u, 0u);
      if (row < SKV_)
        v = *(const uint4*)(src + (size_t)(b * SKV_ + row) * D_ + h * HD_ + c * 8);
      *(uint4*)(dst + row * 88 + c * 8) = v;
    }
  };
  auto stageVT = [&](const unsigned short* src, unsigned short* dst) {
    for (int idx = tid; idx < 384; idx += 256) {
      int kp = idx % 48, c = idx / 48;
      int k0 = kp * 2;
      uint4 a = make_uint4(0u, 0u, 0u, 0u), bb = make_uint4(0u, 0u, 0u, 0u);
      if (k0 < SKV_)
        a = *(const uint4*)(src + (size_t)(b * SKV_ + k0) * D_ + h * HD_ + c * 8);
      if (k0 + 1 < SKV_)
        bb = *(const uint4*)(src + (size_t)(b * SKV_ + k0 + 1) * D_ + h * HD_ + c * 8);
      const unsigned short* ap = (const unsigned short*)&a;
      const unsigned short* bp = (const unsigned short*)&bb;
#pragma unroll
      for (int j = 0; j < 8; ++j) {
        int d = c * 8 + j;
        *(unsigned int*)(dst + d * 104 + k0) =
            (unsigned int)ap[j] | ((unsigned int)bp[j] << 16);
      }
    }
  };

  stageK(Kb, Ks0);
  stageK(Kip, Ks1);
  stageVT(Vb, VT0);
  stageVT(Vip, VT1);

  {
    unsigned short* pw = Ps + wave * 16 * 104;
    int rr = lane >> 2, w4 = lane & 3;
    *(unsigned int*)(pw + rr * 104 + 80 + w4 * 4) = 0u;
    *(unsigned int*)(pw + rr * 104 + 82 + w4 * 4) = 0u;
  }
  __syncthreads();

  struct PVOut { f32x4 a[4]; float inv; };

  auto branch = [&](const unsigned short* KsL, const unsigned short* VTL) -> PVOut {
    f32x4 st[5] = {};
#pragma unroll
    for (int t = 0; t < 5; ++t) {
      const unsigned short* kb = KsL + (t * 16 + l16) * 88 + quad * 8;
      bfrag8 k0 = *(const bfrag8*)(kb);
      bfrag8 k1 = *(const bfrag8*)(kb + 32);
      st[t] = __builtin_amdgcn_mfma_f32_16x16x32_bf16(k0, qf[0], st[t], 0, 0, 0);
      st[t] = __builtin_amdgcn_mfma_f32_16x16x32_bf16(k1, qf[1], st[t], 0, 0, 0);
    }
    float p[5][4];
    float m = -1e30f;
#pragma unroll
    for (int t = 0; t < 5; ++t)
#pragma unroll
      for (int r = 0; r < 4; ++r) {
        float s = st[t][r] * 0.125f;
        if (t == 4 && r >= 1) s = (quad == 3) ? -1e30f : s;
        p[t][r] = s;
        m = fmaxf(m, s);
      }
    m = fmaxf(m, __shfl_xor(m, 16, 64));
    m = fmaxf(m, __shfl_xor(m, 32, 64));
    float l = 0.f;
#pragma unroll
    for (int t = 0; t < 5; ++t)
#pragma unroll
      for (int r = 0; r < 4; ++r) {
        float e = __expf(p[t][r] - m);
        p[t][r] = e;
        l += e;
      }
    l += __shfl_xor(l, 16, 64);
    l += __shfl_xor(l, 32, 64);

    unsigned short* prow = Ps + wave * 16 * 104 + l16 * 104 + quad * 4;
#pragma unroll
    for (int t = 0; t < 5; ++t) {
      __hip_bfloat162 h0 = __float22bfloat162_rn(make_float2(p[t][0], p[t][1]));
      __hip_bfloat162 h1 = __float22bfloat162_rn(make_float2(p[t][2], p[t][3]));
      unsigned int u0, u1;
      __builtin_memcpy(&u0, &h0, 4);
      __builtin_memcpy(&u1, &h1, 4);
      *(unsigned int*)(prow + t * 16) = u0;
      *(unsigned int*)(prow + t * 16 + 2) = u1;
    }
    __syncthreads();

    PVOut o;
    f32x4 acc[4] = {};
    const unsigned short* pbase = Ps + wave * 16 * 104 + l16 * 104;
#pragma unroll
    for (int ks = 0; ks < 3; ++ks) {
      bfrag8 pf = *(const bfrag8*)(pbase + ks * 32 + quad * 8);
#pragma unroll
      for (int dt = 0; dt < 4; ++dt) {
        bfrag8 vf = *(const bfrag8*)(VTL + (dt * 16 + l16) * 104 + ks * 32 + quad * 8);
        acc[dt] = __builtin_amdgcn_mfma_f32_16x16x32_bf16(pf, vf, acc[dt], 0, 0, 0);
      }
    }
#pragma unroll
    for (int dt = 0; dt < 4; ++dt) o.a[dt] = acc[dt];
    o.inv = 1.0f / l;
    return o;
  };

  PVOut o0 = branch(Ks0, VT0);
  __syncthreads();
  PVOut o1 = branch(Ks1, VT1);

  const float boost = boostp[0];
#pragma unroll
  for (int r = 0; r < 4; ++r) {
    const int s = qb + wave * 16 + quad * 4 + r;
    const float sc = mask[s] * boost;
    const float i0 = __shfl(o0.inv, quad * 4 + r, 64);
    const float i1 = __shfl(o1.inv, quad * 4 + r, 64);
    unsigned short* op = hs + (size_t)(b * S_ + s) * D_ + h * HD_ + l16;
#pragma unroll
    for (int dt = 0; dt < 4; ++dt) {
      float v = o0.a[dt][r] * i0 + sc * (o1.a[dt][r] * i1);
      op[dt * 16] = f2bf(v);
    }
  }
}

// ---------------------------------------------------------------------------
extern "C" void kernel_launch(void* const* d_in, const int* in_sizes, int n_in,
                              void* d_out, int out_size, void* d_ws, size_t ws_size,
                              hipStream_t stream) {
  const float* hidden = (const float*)d_in[0];
  const float* enc    = (const float*)d_in[1];
  const float* mask   = (const float*)d_in[2];
  const float* Wq     = (const float*)d_in[3];
  const float* Wk     = (const float*)d_in[4];
  const float* Wv     = (const float*)d_in[5];
  const float* Wkip   = (const float*)d_in[6];
  const float* Wvip   = (const float*)d_in[7];
  const float* Wo     = (const float*)d_in[8];
  const float* bo     = (const float*)d_in[9];

  char* ws = (char*)d_ws;
  unsigned short* cHid  = (unsigned short*)(ws + 0ULL);           // 41,943,040
  unsigned short* hsb   = cHid;                                   // alias (cHid dead after Q-proj)
  unsigned short* cEnc  = (unsigned short*)(ws + 41943040ULL);
  unsigned short* cWqT  = (unsigned short*)(ws + 43204608ULL);    // [N,K] transposed
  unsigned short* cWk   = (unsigned short*)(ws + 46481408ULL);
  unsigned short* cWv   = (unsigned short*)(ws + 51724288ULL);
  unsigned short* cWkip = (unsigned short*)(ws + 56967168ULL);
  unsigned short* cWvip = (unsigned short*)(ws + 62210048ULL);
  unsigned short* cWoT  = (unsigned short*)(ws + 67452928ULL);    // [N,K] transposed
  unsigned short* Qb    = (unsigned short*)(ws + 70729728ULL);
  unsigned short* Kb    = (unsigned short*)(ws + 112672768ULL);
  unsigned short* Vb    = (unsigned short*)(ws + 113461248ULL);
  unsigned short* Kip   = (unsigned short*)(ws + 114249728ULL);
  unsigned short* Vip   = (unsigned short*)(ws + 115038208ULL);
  float* boostp         = (float*)(ws + 115826688ULL);

  // ---- one prep launch: 6 converts + 2 transposes + boost
  {
    PrepArgs a;
    a.csrc[0] = hidden; a.cdst[0] = cHid;  a.cn4[0] = (B_ * S_ * D_) >> 2;
    a.csrc[1] = enc;    a.cdst[1] = cEnc;  a.cn4[1] = (B_ * SKV_ * CD_) >> 2;
    a.csrc[2] = Wk;     a.cdst[2] = cWk;   a.cn4[2] = (CD_ * D_) >> 2;
    a.csrc[3] = Wv;     a.cdst[3] = cWv;   a.cn4[3] = (CD_ * D_) >> 2;
    a.csrc[4] = Wkip;   a.cdst[4] = cWkip; a.cn4[4] = (CD_ * D_) >> 2;
    a.csrc[5] = Wvip;   a.cdst[5] = cWvip; a.cn4[5] = (CD_ * D_) >> 2;
    a.tsrc[0] = Wq; a.tdst[0] = cWqT;
    a.tsrc[1] = Wo; a.tdst[1] = cWoT;
    a.mask = mask; a.boostp = boostp;
    prep_k<<<dim3(2048, 9), dim3(256), 0, stream>>>(a);
  }

  const int MQ = B_ * S_;    // 16384
  const int MKV = B_ * SKV_; // 308

  // Q = hidden @ Wq  -- NEW wide-wave kernel (A/B test vs gemm8p below).
  // grid (16384/128)*(1280/256) = 128*5 = 640, %8==0.
  gemm_wide<<<dim3((MQ / 128) * (D_ / 256)), dim3(256), 0, stream>>>(
      cHid, cWqT, Qb, MQ, D_, D_, nullptr, 0);

  // 4 KV projections in one launch
  {
    KVArgs kv;
    kv.W[0] = cWk;   kv.O[0] = Kb;
    kv.W[1] = cWv;   kv.O[1] = Vb;
    kv.W[2] = cWkip; kv.O[2] = Kip;
    kv.W[3] = cWvip; kv.O[3] = Vip;
    gemm_kv4<<<dim3(5, 20, 4), dim3(256), 0, stream>>>(cEnc, kv, MKV, D_, CD_);
  }

  attn_k<<<dim3(S_ / 64, B_ * H_), dim3(256), 0, stream>>>(Qb, Kb, Vb, Kip, Vip,
                                                           mask, boostp, hsb);

  // out = hsb @ Wo + bo  -- round-3-verified gemm8p (88 us reference).
  // grid (16384/256)*(1280/128) = 64*10 = 640, %8==0.
  gemm8p<<<dim3((MQ / 256) * (D_ / 128)), dim3(512), 0, stream>>>(
      hsb, cWoT, d_out, MQ, D_, D_, bo, 1);
}